// Round 2
// baseline (5635.798 us; speedup 1.0000x reference)
//
#include <hip/hip_runtime.h>
#include <hip/hip_bf16.h>

// ViT forward, MI355X. bf16 MFMA GEMMs (m97-style 128x128 tile, global_load_lds),
// f32 residual/LN/softmax. Adaptive workspace: batch-chunking + attention-pair
// chunking chosen at runtime from ws_size.

typedef unsigned short u16;
typedef __hip_bfloat16 bf16;
typedef __bf16 bf16x8 __attribute__((ext_vector_type(8)));
typedef float f32x4 __attribute__((ext_vector_type(4)));

typedef const __attribute__((address_space(1))) void* gas_ptr;
typedef __attribute__((address_space(3))) void* las_ptr;

#define TOKENS 577
#define TPAD   640
#define DMODEL 512
#define SM_SCALE 0.08838834764831845f   /* 128^-0.5 */

// ---------------------------------------------------------------------------
// Generic bf16 GEMM: C[M,N] = A[M,K] @ Bt[N,K]^T  (+bias) (+gelu)
// OUTMODE 0: C row = m (optionally batched via z strides)
// OUTMODE 1: patch-embed epilogue: row remap b*577+1+t, += pos_emb
// OUTMODE 2: attention-out epilogue: scatter to ob[b*577+t][h*128+c]
// ---------------------------------------------------------------------------
template<int OUTMODE, bool GELU>
__global__ __launch_bounds__(256)
void gemm_bt(const u16* __restrict__ A, int lda, long sAz,
             const u16* __restrict__ Bt, int ldb, long sBz,
             float* __restrict__ Cf, bf16* __restrict__ Cb, int ldc, long sCz,
             const float* __restrict__ bias, const float* __restrict__ pos,
             int K, int rows_valid, int z0)
{
    __shared__ u16 As[128 * 64];
    __shared__ u16 Bs[128 * 64];
    const int tid  = threadIdx.x;
    const int w    = tid >> 6;
    const int lane = tid & 63;
    const int z    = blockIdx.z;
    const u16* Ab = A + (long)z * sAz + (long)blockIdx.y * 128 * lda;
    const u16* Bb = Bt + (long)z * sBz + (long)blockIdx.x * 128 * ldb;
    const int srow = w * 8 + (lane >> 3);   // row within 32-row issue group
    const int scol = (lane & 7) * 8;        // k element offset (16B per lane)
    const int wr = w >> 1, wc = w & 1;
    const int lr = lane & 15, lg = lane >> 4;
    f32x4 acc[4][4] = {};

    for (int kt = 0; kt < K; kt += 64) {
#pragma unroll
        for (int i = 0; i < 4; ++i) {
            const u16* ag = Ab + (long)(i * 32 + srow) * lda + kt + scol;
            const u16* bg = Bb + (long)(i * 32 + srow) * ldb + kt + scol;
            __builtin_amdgcn_global_load_lds((gas_ptr)ag, (las_ptr)&As[(i * 32 + w * 8) * 64], 16, 0, 0);
            __builtin_amdgcn_global_load_lds((gas_ptr)bg, (las_ptr)&Bs[(i * 32 + w * 8) * 64], 16, 0, 0);
        }
        __syncthreads();
#pragma unroll
        for (int kk = 0; kk < 2; ++kk) {
            const int ko = kk * 32 + lg * 8;
            bf16x8 af[4], bv[4];
#pragma unroll
            for (int m = 0; m < 4; ++m)
                af[m] = *(const bf16x8*)&As[(wr * 64 + m * 16 + lr) * 64 + ko];
#pragma unroll
            for (int n = 0; n < 4; ++n)
                bv[n] = *(const bf16x8*)&Bs[(wc * 64 + n * 16 + lr) * 64 + ko];
#pragma unroll
            for (int m = 0; m < 4; ++m)
#pragma unroll
                for (int n = 0; n < 4; ++n)
                    acc[m][n] = __builtin_amdgcn_mfma_f32_16x16x32_bf16(af[m], bv[n], acc[m][n], 0, 0, 0);
        }
        __syncthreads();
    }

    const int cbase = blockIdx.x * 128 + wc * 64;
    const int rbase = blockIdx.y * 128 + wr * 64;
    const int zabs = z0 + z;
#pragma unroll
    for (int n = 0; n < 4; ++n) {
        const int c = cbase + n * 16 + lr;
        const float bval = bias ? bias[c] : 0.0f;
#pragma unroll
        for (int m = 0; m < 4; ++m) {
#pragma unroll
            for (int j = 0; j < 4; ++j) {
                const int r = rbase + m * 16 + lg * 4 + j;
                if (r >= rows_valid) continue;
                float v = acc[m][n][j] + bval;
                if constexpr (GELU) v = 0.5f * v * (1.0f + erff(v * 0.70710678118654752f));
                long idx;
                if constexpr (OUTMODE == 1) {
                    const int pb = r / 576, pt = r - pb * 576;
                    v += pos[(long)(1 + pt) * DMODEL + c];
                    idx = (long)(pb * TOKENS + 1 + pt) * ldc + c;
                } else if constexpr (OUTMODE == 2) {
                    const int bb = zabs >> 2, hh = zabs & 3;
                    idx = (long)(bb * TOKENS + r) * ldc + hh * 128 + c;
                } else {
                    idx = (long)z * sCz + (long)r * ldc + c;
                }
                if (Cf) Cf[idx] = v;
                if (Cb) Cb[idx] = __float2bfloat16(v);
            }
        }
    }
}

// ---------------------------------------------------------------------------
// Weight transpose + f32->bf16:  WT[n][k] = bf16(W[k][n]).  K,N multiples of 32.
// ---------------------------------------------------------------------------
__global__ __launch_bounds__(256)
void wtrans(const float* __restrict__ W, bf16* __restrict__ WT, int K, int N)
{
    __shared__ float tile[32][33];
    const int n0 = blockIdx.x * 32, k0 = blockIdx.y * 32;
    const int tx = threadIdx.x & 31, ty = threadIdx.x >> 5;  // ty 0..7
#pragma unroll
    for (int i = 0; i < 4; ++i)
        tile[ty + i * 8][tx] = W[(long)(k0 + ty + i * 8) * N + n0 + tx];
    __syncthreads();
#pragma unroll
    for (int i = 0; i < 4; ++i)
        WT[(long)(n0 + ty + i * 8) * K + k0 + tx] = __float2bfloat16(tile[tx][ty + i * 8]);
}

// ---------------------------------------------------------------------------
// Patch gather: img (Bc,3,384,384) -> pat[b*576 + x*24+y][p1*48 + p2*3 + c] bf16
// h = p1*24+x, w = p2*24+y  (strided patches per reference rearrange)
// ---------------------------------------------------------------------------
__global__ __launch_bounds__(64)
void patch_gather(const float* __restrict__ img, bf16* __restrict__ pat)
{
    const int bid = blockIdx.x;            // (b, p1, x)
    const int x  = bid % 24;
    const int p1 = (bid / 24) % 16;
    const int b  = bid / (24 * 16);
    __shared__ bf16 lds[24][48];
    const int lane = threadIdx.x;
    const int h = p1 * 24 + x;
    for (int c = 0; c < 3; ++c) {
        const float* row = img + ((long)(b * 3 + c) * 384 + h) * 384;
#pragma unroll
        for (int i = 0; i < 6; ++i) {
            const int wpix = lane + i * 64;
            const float v = row[wpix];
            const int y = wpix % 24, p2 = wpix / 24;
            lds[y][p2 * 3 + c] = __float2bfloat16(v);
        }
    }
    __syncthreads();
    for (int idx = lane; idx < 24 * 48; idx += 64) {
        const int y = idx / 48, j = idx % 48;
        pat[(long)(b * 576 + x * 24 + y) * 768 + p1 * 48 + j] = lds[y][j];
    }
}

// cls token row: tok[b*577][d] = cls[d] + pos[0][d]   (n = Bc*512 threads)
__global__ __launch_bounds__(256)
void clsfill(const float* __restrict__ cls, const float* __restrict__ pos,
             float* __restrict__ tokf, bf16* __restrict__ xb)
{
    const int i = blockIdx.x * 256 + threadIdx.x;
    const int b = i >> 9, d = i & 511;
    const float v = cls[d] + pos[d];
    tokf[(long)b * TOKENS * DMODEL + d] = v;
    xb[(long)b * TOKENS * DMODEL + d] = __float2bfloat16(v);
}

// ---------------------------------------------------------------------------
// qkv[b*577+t][d*12 + kk*4 + h] -> qh/kh[(b*4+h)*640 + t][d]
// ---------------------------------------------------------------------------
__global__ __launch_bounds__(256)
void repack_qk(const u16* __restrict__ qkv, u16* __restrict__ qh, u16* __restrict__ kh)
{
    const int row = blockIdx.x;           // 0..Mrows-1
    const int b = row / TOKENS, t = row % TOKENS;
    const u16* src = qkv + (long)row * 1536;
    const int tid = threadIdx.x;
    const int qk = tid >> 7, h = (tid >> 5) & 3, dg = tid & 31;
    u16 tmp[4];
#pragma unroll
    for (int i = 0; i < 4; ++i)
        tmp[i] = src[(dg * 4 + i) * 12 + qk * 4 + h];
    u16* dst = (qk ? kh : qh) + ((long)((b * 4 + h) * TPAD + t)) * 128 + dg * 4;
    uint2 pk;
    pk.x = (unsigned)tmp[0] | ((unsigned)tmp[1] << 16);
    pk.y = (unsigned)tmp[2] | ((unsigned)tmp[3] << 16);
    *(uint2*)dst = pk;
}

// v -> vhT[(b*4+h)*128 + d][t]  (transposed via LDS). Pad cols stay 0 (region memset).
__global__ __launch_bounds__(256)
void repack_v(const u16* __restrict__ qkv, u16* __restrict__ vhT)
{
    const int bid = blockIdx.x;           // (b,h,tt): Bc*4*10
    const int tt = bid % 10;
    const int h  = (bid / 10) % 4;
    const int b  = bid / 40;
    __shared__ u16 lds[64][128];
    const int tid = threadIdx.x;
    const int tl = tid >> 2, dg = tid & 3;
    const long row = (long)b * TOKENS + tt * 64 + tl;   // may spill into pad rows (in-bounds)
    const u16* src = qkv + row * 1536;
#pragma unroll
    for (int j = 0; j < 32; ++j) {
        const int d = dg * 32 + j;
        lds[tl][d] = src[d * 12 + 8 + h];
    }
    __syncthreads();
    const int d = tid >> 1, th = (tid & 1) * 32;
    u16* dst = vhT + ((long)((b * 4 + h) * 128 + d)) * TPAD + tt * 64 + th;
#pragma unroll
    for (int j = 0; j < 32; ++j) {
        const int t = tt * 64 + th + j;
        if (t < TOKENS) dst[j] = lds[th + j][d];
    }
}

// ---------------------------------------------------------------------------
// Row softmax over S (f32, ld=640, valid cols < 577), scale applied, out bf16 P
// Writes exact 0 for cols >= 577 so padded-K PV contributions vanish.
// ---------------------------------------------------------------------------
__global__ __launch_bounds__(256)
void softmax_rows(const float* __restrict__ S, bf16* __restrict__ P, int nrows)
{
    const int row = blockIdx.x * 4 + (threadIdx.x >> 6);
    if (row >= nrows) return;
    const int lane = threadIdx.x & 63;
    const float* s = S + (long)row * TPAD;
    float v[10];
    float mx = -1e30f;
#pragma unroll
    for (int i = 0; i < 10; ++i) {
        const int c = lane + i * 64;
        v[i] = (c < TOKENS) ? s[c] * SM_SCALE : -1e30f;
        mx = fmaxf(mx, v[i]);
    }
#pragma unroll
    for (int o = 32; o; o >>= 1) mx = fmaxf(mx, __shfl_xor(mx, o));
    float sum = 0.f;
#pragma unroll
    for (int i = 0; i < 10; ++i) { v[i] = __expf(v[i] - mx); sum += v[i]; }
#pragma unroll
    for (int o = 32; o; o >>= 1) sum += __shfl_xor(sum, o);
    const float inv = 1.f / sum;
#pragma unroll
    for (int i = 0; i < 10; ++i) {
        const int c = lane + i * 64;
        P[(long)row * TPAD + c] = __float2bfloat16(v[i] * inv);
    }
}

// ---------------------------------------------------------------------------
// y = LN(xin + res)*g + b  -> outf (f32, may alias res) and outb (bf16)
// ---------------------------------------------------------------------------
__global__ __launch_bounds__(256)
void resln(const float* __restrict__ xin, const float* __restrict__ res,
           const float* __restrict__ g, const float* __restrict__ b,
           float* __restrict__ outf, bf16* __restrict__ outb, int nrows)
{
    const int row = blockIdx.x * 4 + (threadIdx.x >> 6);
    if (row >= nrows) return;
    const int lane = threadIdx.x & 63;
    const float* p1 = xin + (long)row * DMODEL;
    const float* p2 = res + (long)row * DMODEL;
    float v[8];
    float s = 0.f;
#pragma unroll
    for (int i = 0; i < 8; ++i) { v[i] = p1[lane + i * 64] + p2[lane + i * 64]; s += v[i]; }
#pragma unroll
    for (int o = 32; o; o >>= 1) s += __shfl_xor(s, o);
    const float mean = s * (1.f / 512.f);
    float q = 0.f;
#pragma unroll
    for (int i = 0; i < 8; ++i) { const float d = v[i] - mean; q += d * d; }
#pragma unroll
    for (int o = 32; o; o >>= 1) q += __shfl_xor(q, o);
    const float rs = rsqrtf(q * (1.f / 512.f) + 1e-5f);
#pragma unroll
    for (int i = 0; i < 8; ++i) {
        const int c = lane + i * 64;
        const float o = (v[i] - mean) * rs * g[c] + b[c];
        outf[(long)row * DMODEL + c] = o;
        outb[(long)row * DMODEL + c] = __float2bfloat16(o);
    }
}

// Head: out[b][c] = tok[b*577][:] . Whead[:,c] + bhead[c]   (f32)
__global__ __launch_bounds__(64)
void head_k(const float* __restrict__ tokf, const float* __restrict__ Wh,
            const float* __restrict__ bh, float* __restrict__ out)
{
    const int b = blockIdx.x;
    const int lane = threadIdx.x;
    const float* x = tokf + (long)b * TOKENS * DMODEL;
    float acc[10] = {};
#pragma unroll
    for (int i = 0; i < 8; ++i) {
        const int d = lane + i * 64;
        const float xv = x[d];
        const float* wr = Wh + (long)d * 10;
#pragma unroll
        for (int c = 0; c < 10; ++c) acc[c] += xv * wr[c];
    }
#pragma unroll
    for (int c = 0; c < 10; ++c)
#pragma unroll
        for (int o = 32; o; o >>= 1) acc[c] += __shfl_xor(acc[c], o);
    if (lane == 0) {
#pragma unroll
        for (int c = 0; c < 10; ++c) out[b * 10 + c] = acc[c] + bh[c];
    }
}

// ---------------------------------------------------------------------------
extern "C" void kernel_launch(void* const* d_in, const int* in_sizes, int n_in,
                              void* d_out, int out_size, void* d_ws, size_t ws_size,
                              hipStream_t stream)
{
    (void)in_sizes; (void)n_in; (void)out_size;
    const float* img    = (const float*)d_in[0];
    const float* Wpatch = (const float*)d_in[1];
    const float* bpatch = (const float*)d_in[2];
    const float* clstk  = (const float*)d_in[3];
    const float* pos    = (const float*)d_in[4];
    const float* Wqkv   = (const float*)d_in[5];
    const float* W0     = (const float*)d_in[6];
    const float* g1     = (const float*)d_in[7];
    const float* b1     = (const float*)d_in[8];
    const float* g2     = (const float*)d_in[9];
    const float* b2     = (const float*)d_in[10];
    const float* W1     = (const float*)d_in[11];
    const float* bb1    = (const float*)d_in[12];
    const float* W2     = (const float*)d_in[13];
    const float* bb2    = (const float*)d_in[14];
    const float* Whead  = (const float*)d_in[15];
    const float* bhead  = (const float*)d_in[16];

    // ---- pick the largest (batch-chunk, attn-pair-chunk) config that fits ws ----
    static const int cand[][2] = {{32,32},{32,16},{32,8},{16,8},{16,4},
                                  {8,4},{8,2},{4,2},{2,2},{1,1}};
    int Bc = 0, ZP = 0;
    size_t o_tokf=0, o_xb=0, o_R1=0, o_R2=0, o_R3=0, o_wp=0, o_wr=0;
    for (int ci = 0; ci < 10; ++ci) {
        const int bc = cand[ci][0], zp = cand[ci][1];
        const long Mrows = (long)bc * TOKENS;
        const long Mpad  = ((Mrows + 127) / 128) * 128;
        const long NP    = bc * 4;
        size_t off = 0;
        auto take = [&](size_t sz) { size_t o = off; off += (sz + 255) & ~(size_t)255; return o; };
        size_t t_tokf = take((size_t)Mpad * 512 * 4);
        size_t t_xb   = take((size_t)Mpad * 512 * 2);
        size_t t_R1   = take((size_t)Mpad * 2048 * 2);           // qkvb | pat | ob | h1b
        size_t r2 = (size_t)3 * NP * TPAD * 128 * 2;             // qh,kh,vhT
        size_t t1b = (size_t)Mpad * 512 * 4;                     // t1 (f32)
        size_t t_R2 = take(r2 > t1b ? r2 : t1b);
        size_t t_R3 = take((size_t)zp * TPAD * TPAD * 6);        // S (f32) + P (bf16)
        size_t t_wp = take((size_t)512 * 768 * 2);
        size_t t_wr = take((size_t)3145728 * 2);                 // rotating layer weights
        if (off <= ws_size) {
            Bc = bc; ZP = zp;
            o_tokf = t_tokf; o_xb = t_xb; o_R1 = t_R1; o_R2 = t_R2;
            o_R3 = t_R3; o_wp = t_wp; o_wr = t_wr;
            break;
        }
    }
    if (Bc == 0) return;

    const long Mrows = (long)Bc * TOKENS;
    const long Mpad  = ((Mrows + 127) / 128) * 128;
    const long NP    = Bc * 4;
    const int  gy    = (int)(Mpad / 128);
    const long patRows = ((long)Bc * 576 + 127) / 128 * 128;

    char* base = (char*)d_ws;
    float* tokf = (float*)(base + o_tokf);
    bf16*  xb   = (bf16*)(base + o_xb);
    char*  R1   = base + o_R1;
    char*  R2   = base + o_R2;
    char*  R3   = base + o_R3;
    bf16*  wpT  = (bf16*)(base + o_wp);
    bf16*  wqkvT = (bf16*)(base + o_wr);
    bf16*  w0T   = wqkvT + 1536 * 512;
    bf16*  w1T   = w0T   + 512 * 512;
    bf16*  w2T   = w1T   + 2048 * 512;

    u16*  qkvb = (u16*)R1;
    bf16* pat  = (bf16*)R1;
    bf16* ob   = (bf16*)R1;
    u16*  h1b  = (u16*)R1;
    u16*  qh   = (u16*)R2;
    u16*  kh   = qh + (size_t)NP * TPAD * 128;
    u16*  vhT  = kh + (size_t)NP * TPAD * 128;
    float* t1  = (float*)R2;
    float* Ssc = (float*)R3;
    bf16*  Psc = (bf16*)(R3 + (size_t)ZP * TPAD * TPAD * 4);

    auto wt = [&](const float* W, bf16* WT, int K, int N) {
        wtrans<<<dim3(N / 32, K / 32), 256, 0, stream>>>(W, WT, K, N);
    };
    wt(Wpatch, wpT, 768, 512);   // once: persistent across chunks

    const int nchunks = 32 / Bc;
    for (int ch = 0; ch < nchunks; ++ch) {
        const float* img_c = img + (long)ch * Bc * 3 * 384 * 384;

        // embed
        hipMemsetAsync(xb, 0, (size_t)Mpad * 512 * 2, stream);   // pad rows -> exact 0
        clsfill<<<Bc * 2, 256, 0, stream>>>(clstk, pos, tokf, xb);
        patch_gather<<<Bc * 16 * 24, 64, 0, stream>>>(img_c, pat);
        gemm_bt<1, false><<<dim3(4, (int)(patRows / 128), 1), 256, 0, stream>>>(
            (const u16*)pat, 768, 0, (const u16*)wpT, 768, 0,
            tokf, xb, 512, 0, bpatch, pos, 768, Bc * 576, 0);

        for (int l = 0; l < 6; ++l) {
            // rotate this layer's weights to bf16 N x K
            wt(Wqkv + (long)l * 512 * 1536, wqkvT, 512, 1536);
            wt(W0 + (long)l * 512 * 512,  w0T, 512, 512);
            wt(W1 + (long)l * 512 * 2048, w1T, 512, 2048);
            wt(W2 + (long)l * 2048 * 512, w2T, 2048, 512);

            // qkv = x @ Wqkv (interleaved layout; pad rows = 0 since xb pads are 0)
            gemm_bt<0, false><<<dim3(12, gy, 1), 256, 0, stream>>>(
                (const u16*)xb, 512, 0, (const u16*)wqkvT, 512, 0,
                nullptr, (bf16*)qkvb, 1536, 0, nullptr, nullptr, 512, (int)Mpad, 0);

            // zero q/k/v head buffers (pad token rows/cols must be exact 0)
            hipMemsetAsync(qh, 0, (size_t)3 * NP * TPAD * 128 * 2, stream);
            repack_qk<<<(int)Mrows, 256, 0, stream>>>(qkvb, qh, kh);
            repack_v<<<(int)(NP * 10), 256, 0, stream>>>(qkvb, vhT);

            // attention in pair-chunks
            for (int z0 = 0; z0 < NP; z0 += ZP) {
                const int zc = (int)((NP - z0) < ZP ? (NP - z0) : ZP);
                gemm_bt<0, false><<<dim3(5, 5, zc), 256, 0, stream>>>(
                    qh + (long)z0 * TPAD * 128, 128, (long)TPAD * 128,
                    kh + (long)z0 * TPAD * 128, 128, (long)TPAD * 128,
                    Ssc, nullptr, TPAD, (long)TPAD * TPAD, nullptr, nullptr, 128, TPAD, 0);
                softmax_rows<<<(zc * TPAD) / 4, 256, 0, stream>>>(Ssc, Psc, zc * TPAD);
                gemm_bt<2, false><<<dim3(1, 5, zc), 256, 0, stream>>>(
                    (const u16*)Psc, TPAD, (long)TPAD * TPAD,
                    vhT + (long)z0 * 128 * TPAD, TPAD, (long)128 * TPAD,
                    nullptr, ob, 512, 0, nullptr, nullptr, TPAD, TOKENS, z0);
            }

            // proj: t1 = o @ W0   (t1 aliases qh/kh/vhT — attention done)
            gemm_bt<0, false><<<dim3(4, gy, 1), 256, 0, stream>>>(
                (const u16*)ob, 512, 0, (const u16*)w0T, 512, 0,
                t1, nullptr, 512, 0, nullptr, nullptr, 512, (int)Mrows, 0);
            // y = LN(t1 + x) -> tokf (in place), xb
            resln<<<(int)((Mrows + 3) / 4), 256, 0, stream>>>(
                t1, tokf, g1 + l * 512, b1 + l * 512, tokf, xb, (int)Mrows);
            // h1 = gelu(y @ W1 + bb1)  (h1b overwrites ob/qkvb — both dead)
            gemm_bt<0, true><<<dim3(16, gy, 1), 256, 0, stream>>>(
                (const u16*)xb, 512, 0, (const u16*)w1T, 512, 0,
                nullptr, (bf16*)h1b, 2048, 0, bb1 + l * 2048, nullptr, 512, (int)Mpad, 0);
            // t1 = h1 @ W2 + bb2
            gemm_bt<0, false><<<dim3(4, gy, 1), 256, 0, stream>>>(
                (const u16*)h1b, 2048, 0, (const u16*)w2T, 2048, 0,
                t1, nullptr, 512, 0, bb2 + l * 512, nullptr, 2048, (int)Mrows, 0);
            // x = LN(t1 + y) -> tokf, xb
            resln<<<(int)((Mrows + 3) / 4), 256, 0, stream>>>(
                t1, tokf, g2 + l * 512, b2 + l * 512, tokf, xb, (int)Mrows);
        }

        head_k<<<Bc, 64, 0, stream>>>(tokf, Whead, bhead, (float*)d_out + (long)ch * Bc * 10);
    }
}

// Round 3
// 3293.299 us; speedup vs baseline: 1.7113x; 1.7113x over previous
//
#include <hip/hip_runtime.h>
#include <hip/hip_bf16.h>

// ViT forward, MI355X. bf16 MFMA GEMMs (m97-style 128x128 tile, global_load_lds),
// fused flash attention (QK^T -> online softmax -> PV in one kernel),
// f32 residual/LN. Adaptive workspace via batch chunking.

typedef unsigned short u16;
typedef __hip_bfloat16 bf16;
typedef __bf16 bf16x8 __attribute__((ext_vector_type(8)));
typedef float f32x4 __attribute__((ext_vector_type(4)));

typedef const __attribute__((address_space(1))) void* gas_ptr;
typedef __attribute__((address_space(3))) void* las_ptr;

#define TOKENS 577
#define TPAD   640
#define DMODEL 512
#define SM_SCALE 0.08838834764831845f   /* 128^-0.5 */

static __device__ __forceinline__ u16 f2b(float v) {
    bf16 t = __float2bfloat16(v);
    return *(u16*)&t;
}

// ---------------------------------------------------------------------------
// Generic bf16 GEMM: C[M,N] = A[M,K] @ Bt[N,K]^T  (+bias) (+gelu)
// OUTMODE 0: C row = m
// OUTMODE 1: patch-embed epilogue: row remap b*577+1+t, += pos_emb
// ---------------------------------------------------------------------------
template<int OUTMODE, bool GELU>
__global__ __launch_bounds__(256)
void gemm_bt(const u16* __restrict__ A, int lda,
             const u16* __restrict__ Bt, int ldb,
             float* __restrict__ Cf, bf16* __restrict__ Cb, int ldc,
             const float* __restrict__ bias, const float* __restrict__ pos,
             int K, int rows_valid)
{
    __shared__ u16 As[128 * 64];
    __shared__ u16 Bs[128 * 64];
    const int tid  = threadIdx.x;
    const int w    = tid >> 6;
    const int lane = tid & 63;
    const u16* Ab = A + (long)blockIdx.y * 128 * lda;
    const u16* Bb = Bt + (long)blockIdx.x * 128 * ldb;
    const int srow = w * 8 + (lane >> 3);
    const int scol = (lane & 7) * 8;
    const int wr = w >> 1, wc = w & 1;
    const int lr = lane & 15, lg = lane >> 4;
    f32x4 acc[4][4] = {};

    for (int kt = 0; kt < K; kt += 64) {
#pragma unroll
        for (int i = 0; i < 4; ++i) {
            const u16* ag = Ab + (long)(i * 32 + srow) * lda + kt + scol;
            const u16* bg = Bb + (long)(i * 32 + srow) * ldb + kt + scol;
            __builtin_amdgcn_global_load_lds((gas_ptr)ag, (las_ptr)&As[(i * 32 + w * 8) * 64], 16, 0, 0);
            __builtin_amdgcn_global_load_lds((gas_ptr)bg, (las_ptr)&Bs[(i * 32 + w * 8) * 64], 16, 0, 0);
        }
        __syncthreads();
#pragma unroll
        for (int kk = 0; kk < 2; ++kk) {
            const int ko = kk * 32 + lg * 8;
            bf16x8 af[4], bv[4];
#pragma unroll
            for (int m = 0; m < 4; ++m)
                af[m] = *(const bf16x8*)&As[(wr * 64 + m * 16 + lr) * 64 + ko];
#pragma unroll
            for (int n = 0; n < 4; ++n)
                bv[n] = *(const bf16x8*)&Bs[(wc * 64 + n * 16 + lr) * 64 + ko];
#pragma unroll
            for (int m = 0; m < 4; ++m)
#pragma unroll
                for (int n = 0; n < 4; ++n)
                    acc[m][n] = __builtin_amdgcn_mfma_f32_16x16x32_bf16(af[m], bv[n], acc[m][n], 0, 0, 0);
        }
        __syncthreads();
    }

    const int cbase = blockIdx.x * 128 + wc * 64;
    const int rbase = blockIdx.y * 128 + wr * 64;
#pragma unroll
    for (int n = 0; n < 4; ++n) {
        const int c = cbase + n * 16 + lr;
        const float bval = bias ? bias[c] : 0.0f;
#pragma unroll
        for (int m = 0; m < 4; ++m) {
#pragma unroll
            for (int j = 0; j < 4; ++j) {
                const int r = rbase + m * 16 + lg * 4 + j;
                if (r >= rows_valid) continue;
                float v = acc[m][n][j] + bval;
                if constexpr (GELU) v = 0.5f * v * (1.0f + erff(v * 0.70710678118654752f));
                long idx;
                if constexpr (OUTMODE == 1) {
                    const int pb = r / 576, pt = r - pb * 576;
                    v += pos[(long)(1 + pt) * DMODEL + c];
                    idx = (long)(pb * TOKENS + 1 + pt) * ldc + c;
                } else {
                    idx = (long)r * ldc + c;
                }
                if (Cf) Cf[idx] = v;
                if (Cb) Cb[idx] = __float2bfloat16(v);
            }
        }
    }
}

// ---------------------------------------------------------------------------
// Fused flash attention. Grid: (5 q-tiles, NP pairs). 256 threads = 4 waves,
// each wave owns 32 q rows. LDS: K/P tile (32KB) + V^T tile (32KB).
// qkv layout (permuted): [row][ kk*512 + h*128 + d ], row = b*577 + t (+pad).
// ---------------------------------------------------------------------------
__global__ __launch_bounds__(256, 2)
void attn_flash(const u16* __restrict__ qkv, const u16* __restrict__ vhT,
                bf16* __restrict__ ob)
{
    __shared__ u16 ldsA[128 * 128];   // K tile, then P tile
    __shared__ u16 ldsB[128 * 128];   // V^T tile [d][kv]
    const int tid = threadIdx.x;
    const int w = tid >> 6, lane = tid & 63;
    const int lr = lane & 15, lg = lane >> 4;
    const int pair = blockIdx.y;
    const int b = pair >> 2, h = pair & 3;
    const int q0 = blockIdx.x * 128;
    const long rowbase = (long)b * TOKENS;

    // Q fragments in registers: q = w*32 + m*16 + lr, d = kf*32 + lg*8 + j
    bf16x8 qf[2][4];
#pragma unroll
    for (int m = 0; m < 2; ++m)
#pragma unroll
        for (int kf = 0; kf < 4; ++kf) {
            const long r = rowbase + q0 + w * 32 + m * 16 + lr;
            qf[m][kf] = *(const bf16x8*)&qkv[r * 1536 + h * 128 + kf * 32 + lg * 8];
        }

    float mrun[2][4], lrun[2][4];
#pragma unroll
    for (int m = 0; m < 2; ++m)
#pragma unroll
        for (int j = 0; j < 4; ++j) { mrun[m][j] = -1e30f; lrun[m][j] = 0.f; }
    f32x4 oacc[2][8] = {};

    for (int kv0 = 0; kv0 < TPAD; kv0 += 128) {
        // stage K tile [kv][d] and V^T tile [d][kv]
        {
            const u16* kg = qkv + (rowbase + kv0) * 1536 + 512 + h * 128;
            const u16* vg = vhT + ((long)pair * 128) * TPAD + kv0;
#pragma unroll
            for (int p = 0; p < 8; ++p) {
                const int i = p * 16 + w * 4 + lg;
                __builtin_amdgcn_global_load_lds((gas_ptr)(kg + (long)i * 1536 + lr * 8),
                                                 (las_ptr)&ldsA[(p * 16 + w * 4) * 128], 16, 0, 0);
                __builtin_amdgcn_global_load_lds((gas_ptr)(vg + (long)i * TPAD + lr * 8),
                                                 (las_ptr)&ldsB[(p * 16 + w * 4) * 128], 16, 0, 0);
            }
        }
        __syncthreads();

        // S = Q K^T : per wave 32q x 128kv
        f32x4 s[2][8] = {};
#pragma unroll
        for (int kf = 0; kf < 4; ++kf) {
            bf16x8 bv[8];
#pragma unroll
            for (int n = 0; n < 8; ++n)
                bv[n] = *(const bf16x8*)&ldsA[(n * 16 + lr) * 128 + kf * 32 + lg * 8];
#pragma unroll
            for (int m = 0; m < 2; ++m)
#pragma unroll
                for (int n = 0; n < 8; ++n)
                    s[m][n] = __builtin_amdgcn_mfma_f32_16x16x32_bf16(qf[m][kf], bv[n], s[m][n], 0, 0, 0);
        }

        // online softmax (per q row: col=lane&15 within n-tile, row=(lane>>4)*4+jj)
        float sc[2][4];
#pragma unroll
        for (int m = 0; m < 2; ++m)
#pragma unroll
            for (int jj = 0; jj < 4; ++jj) {
                float mx = mrun[m][jj];
#pragma unroll
                for (int n = 0; n < 8; ++n) {
                    const int col = kv0 + n * 16 + lr;
                    float v = s[m][n][jj] * SM_SCALE;
                    v = (col < TOKENS) ? v : -1e30f;
                    s[m][n][jj] = v;
                    mx = fmaxf(mx, v);
                }
#pragma unroll
                for (int o = 1; o < 16; o <<= 1) mx = fmaxf(mx, __shfl_xor(mx, o));
                const float f = __expf(mrun[m][jj] - mx);
                sc[m][jj] = f;
                float sum = 0.f;
#pragma unroll
                for (int n = 0; n < 8; ++n) {
                    const float p = __expf(s[m][n][jj] - mx);
                    s[m][n][jj] = p;
                    sum += p;
                }
#pragma unroll
                for (int o = 1; o < 16; o <<= 1) sum += __shfl_xor(sum, o);
                lrun[m][jj] = lrun[m][jj] * f + sum;
                mrun[m][jj] = mx;
            }
        // rescale O
#pragma unroll
        for (int m = 0; m < 2; ++m)
#pragma unroll
            for (int n = 0; n < 8; ++n)
#pragma unroll
                for (int jj = 0; jj < 4; ++jj) oacc[m][n][jj] *= sc[m][jj];

        __syncthreads();   // all waves done reading K from ldsA
        // write P tile [q][kv] bf16 into ldsA (C layout -> row-major)
#pragma unroll
        for (int m = 0; m < 2; ++m)
#pragma unroll
            for (int n = 0; n < 8; ++n)
#pragma unroll
                for (int jj = 0; jj < 4; ++jj)
                    ldsA[(w * 32 + m * 16 + lg * 4 + jj) * 128 + n * 16 + lr] = f2b(s[m][n][jj]);
        __syncthreads();

        // O += P V : A = P (rows q), B = V^T (rows d)
#pragma unroll
        for (int kf = 0; kf < 4; ++kf) {
            bf16x8 pa[2];
#pragma unroll
            for (int m = 0; m < 2; ++m)
                pa[m] = *(const bf16x8*)&ldsA[(w * 32 + m * 16 + lr) * 128 + kf * 32 + lg * 8];
#pragma unroll
            for (int n = 0; n < 8; ++n) {
                const bf16x8 vb = *(const bf16x8*)&ldsB[(n * 16 + lr) * 128 + kf * 32 + lg * 8];
#pragma unroll
                for (int m = 0; m < 2; ++m)
                    oacc[m][n] = __builtin_amdgcn_mfma_f32_16x16x32_bf16(pa[m], vb, oacc[m][n], 0, 0, 0);
            }
        }
        __syncthreads();   // before next stage overwrites LDS
    }

    // epilogue: O /= l, write ob[b*577+q][h*128+d]
#pragma unroll
    for (int m = 0; m < 2; ++m)
#pragma unroll
        for (int jj = 0; jj < 4; ++jj) {
            const float inv = 1.f / lrun[m][jj];
            const int q = q0 + w * 32 + m * 16 + lg * 4 + jj;
            if (q >= TOKENS) continue;
#pragma unroll
            for (int n = 0; n < 8; ++n)
                ob[(rowbase + q) * DMODEL + h * 128 + n * 16 + lr] =
                    __float2bfloat16(oacc[m][n][jj] * inv);
        }
}

// ---------------------------------------------------------------------------
// Weight transpose + f32->bf16:  WT[n][k] = bf16(W[k][n]).  K,N multiples of 32.
// QKVPERM: output row n' = kk*512 + h*128 + d  for original col n = d*12+kk*4+h
// ---------------------------------------------------------------------------
template<bool QKVPERM>
__global__ __launch_bounds__(256)
void wtrans(const float* __restrict__ W, bf16* __restrict__ WT, int K, int N)
{
    __shared__ float tile[32][33];
    const int n0 = blockIdx.x * 32, k0 = blockIdx.y * 32;
    const int tx = threadIdx.x & 31, ty = threadIdx.x >> 5;
#pragma unroll
    for (int i = 0; i < 4; ++i)
        tile[ty + i * 8][tx] = W[(long)(k0 + ty + i * 8) * N + n0 + tx];
    __syncthreads();
#pragma unroll
    for (int i = 0; i < 4; ++i) {
        int n = n0 + ty + i * 8;
        if constexpr (QKVPERM) {
            const int d = n / 12, r = n % 12;
            n = (r >> 2) * 512 + (r & 3) * 128 + d;
        }
        WT[(long)n * K + k0 + tx] = __float2bfloat16(tile[tx][ty + i * 8]);
    }
}

// ---------------------------------------------------------------------------
// Patch gather: img (Bc,3,384,384) -> pat[b*576 + x*24+y][p1*48 + p2*3 + c] bf16
// ---------------------------------------------------------------------------
__global__ __launch_bounds__(64)
void patch_gather(const float* __restrict__ img, bf16* __restrict__ pat)
{
    const int bid = blockIdx.x;
    const int x  = bid % 24;
    const int p1 = (bid / 24) % 16;
    const int b  = bid / (24 * 16);
    __shared__ bf16 lds[24][48];
    const int lane = threadIdx.x;
    const int h = p1 * 24 + x;
    for (int c = 0; c < 3; ++c) {
        const float* row = img + ((long)(b * 3 + c) * 384 + h) * 384;
#pragma unroll
        for (int i = 0; i < 6; ++i) {
            const int wpix = lane + i * 64;
            const float v = row[wpix];
            const int y = wpix % 24, p2 = wpix / 24;
            lds[y][p2 * 3 + c] = __float2bfloat16(v);
        }
    }
    __syncthreads();
    for (int idx = lane; idx < 24 * 48; idx += 64) {
        const int y = idx / 48, j = idx % 48;
        pat[(long)(b * 576 + x * 24 + y) * 768 + p1 * 48 + j] = lds[y][j];
    }
}

// cls token row
__global__ __launch_bounds__(256)
void clsfill(const float* __restrict__ cls, const float* __restrict__ pos,
             float* __restrict__ tokf, bf16* __restrict__ xb)
{
    const int i = blockIdx.x * 256 + threadIdx.x;
    const int b = i >> 9, d = i & 511;
    const float v = cls[d] + pos[d];
    tokf[(long)b * TOKENS * DMODEL + d] = v;
    xb[(long)b * TOKENS * DMODEL + d] = __float2bfloat16(v);
}

// ---------------------------------------------------------------------------
// v (qkv permuted col 1024 + h*128 + d) -> vhT[(pair)*128 + d][t], t>=577 -> 0
// ---------------------------------------------------------------------------
__global__ __launch_bounds__(256)
void repack_v(const u16* __restrict__ qkv, u16* __restrict__ vhT)
{
    __shared__ u16 lds[64][136];
    const int bid = blockIdx.x;               // (pair, tt)
    const int tt = bid % 10, pair = bid / 10;
    const int b = pair >> 2, h = pair & 3;
    const int tid = threadIdx.x;
    const int tl = tid >> 2, seg = tid & 3;
    const long row = (long)b * TOKENS + tt * 64 + tl;
    const u16* src = qkv + row * 1536 + 1024 + h * 128 + seg * 32;
#pragma unroll
    for (int u = 0; u < 4; ++u)
        *(uint4*)&lds[tl][seg * 32 + u * 8] = *(const uint4*)&src[u * 8];
    __syncthreads();
    const int d = tid >> 1, th = (tid & 1) * 32;
    u16* dst = vhT + ((long)pair * 128 + d) * TPAD + tt * 64 + th;
#pragma unroll
    for (int blk = 0; blk < 4; ++blk) {
        uint4 pk; u16* pp = (u16*)&pk;
#pragma unroll
        for (int j = 0; j < 8; ++j) {
            const int t = tt * 64 + th + blk * 8 + j;
            pp[j] = (t < TOKENS) ? lds[th + blk * 8 + j][d] : (u16)0;
        }
        *(uint4*)&dst[blk * 8] = pk;
    }
}

// ---------------------------------------------------------------------------
// y = LN(xin + res)*g + b  -> outf (may alias res) and outb (bf16)
// ---------------------------------------------------------------------------
__global__ __launch_bounds__(256)
void resln(const float* __restrict__ xin, const float* __restrict__ res,
           const float* __restrict__ g, const float* __restrict__ b,
           float* __restrict__ outf, bf16* __restrict__ outb, int nrows)
{
    const int row = blockIdx.x * 4 + (threadIdx.x >> 6);
    if (row >= nrows) return;
    const int lane = threadIdx.x & 63;
    const float* p1 = xin + (long)row * DMODEL;
    const float* p2 = res + (long)row * DMODEL;
    float v[8];
    float s = 0.f;
#pragma unroll
    for (int i = 0; i < 8; ++i) { v[i] = p1[lane + i * 64] + p2[lane + i * 64]; s += v[i]; }
#pragma unroll
    for (int o = 32; o; o >>= 1) s += __shfl_xor(s, o);
    const float mean = s * (1.f / 512.f);
    float q = 0.f;
#pragma unroll
    for (int i = 0; i < 8; ++i) { const float d = v[i] - mean; q += d * d; }
#pragma unroll
    for (int o = 32; o; o >>= 1) q += __shfl_xor(q, o);
    const float rs = rsqrtf(q * (1.f / 512.f) + 1e-5f);
#pragma unroll
    for (int i = 0; i < 8; ++i) {
        const int c = lane + i * 64;
        const float o = (v[i] - mean) * rs * g[c] + b[c];
        outf[(long)row * DMODEL + c] = o;
        outb[(long)row * DMODEL + c] = __float2bfloat16(o);
    }
}

// Head: out[b][c] = tok[b*577][:] . Whead[:,c] + bhead[c]
__global__ __launch_bounds__(64)
void head_k(const float* __restrict__ tokf, const float* __restrict__ Wh,
            const float* __restrict__ bh, float* __restrict__ out)
{
    const int b = blockIdx.x;
    const int lane = threadIdx.x;
    const float* x = tokf + (long)b * TOKENS * DMODEL;
    float acc[10] = {};
#pragma unroll
    for (int i = 0; i < 8; ++i) {
        const int d = lane + i * 64;
        const float xv = x[d];
        const float* wr = Wh + (long)d * 10;
#pragma unroll
        for (int c = 0; c < 10; ++c) acc[c] += xv * wr[c];
    }
#pragma unroll
    for (int c = 0; c < 10; ++c)
#pragma unroll
        for (int o = 32; o; o >>= 1) acc[c] += __shfl_xor(acc[c], o);
    if (lane == 0) {
#pragma unroll
        for (int c = 0; c < 10; ++c) out[b * 10 + c] = acc[c] + bh[c];
    }
}

// ---------------------------------------------------------------------------
extern "C" void kernel_launch(void* const* d_in, const int* in_sizes, int n_in,
                              void* d_out, int out_size, void* d_ws, size_t ws_size,
                              hipStream_t stream)
{
    (void)in_sizes; (void)n_in; (void)out_size;
    const float* img    = (const float*)d_in[0];
    const float* Wpatch = (const float*)d_in[1];
    const float* bpatch = (const float*)d_in[2];
    const float* clstk  = (const float*)d_in[3];
    const float* pos    = (const float*)d_in[4];
    const float* Wqkv   = (const float*)d_in[5];
    const float* W0     = (const float*)d_in[6];
    const float* g1     = (const float*)d_in[7];
    const float* b1     = (const float*)d_in[8];
    const float* g2     = (const float*)d_in[9];
    const float* b2     = (const float*)d_in[10];
    const float* W1     = (const float*)d_in[11];
    const float* bb1    = (const float*)d_in[12];
    const float* W2     = (const float*)d_in[13];
    const float* bb2    = (const float*)d_in[14];
    const float* Whead  = (const float*)d_in[15];
    const float* bhead  = (const float*)d_in[16];

    // ---- pick the largest batch chunk that fits ws ----
    static const int cand[6] = {32, 16, 8, 4, 2, 1};
    int Bc = 0;
    size_t o_tokf=0, o_xb=0, o_R1=0, o_R2=0, o_ob=0, o_wp=0, o_wr=0;
    for (int ci = 0; ci < 6; ++ci) {
        const int bc = cand[ci];
        const long Mrows = (long)bc * TOKENS;
        const long Mpad  = ((Mrows + 127) / 128) * 128;
        size_t off = 0;
        auto take = [&](size_t sz) { size_t o = off; off += (sz + 255) & ~(size_t)255; return o; };
        size_t t_tokf = take((size_t)Mpad * 512 * 4);
        size_t t_xb   = take((size_t)Mpad * 512 * 2);
        size_t t_R1   = take((size_t)Mpad * 2048 * 2);          // pat | qkv | h1b
        size_t t_R2   = take((size_t)Mpad * 512 * 4);           // vhT | t1
        size_t t_ob   = take((size_t)Mpad * 512 * 2);
        size_t t_wp   = take((size_t)512 * 768 * 2);
        size_t t_wr   = take((size_t)3145728 * 2);              // rotating layer weights
        if (off <= ws_size) {
            Bc = bc;
            o_tokf=t_tokf; o_xb=t_xb; o_R1=t_R1; o_R2=t_R2; o_ob=t_ob; o_wp=t_wp; o_wr=t_wr;
            break;
        }
    }
    if (Bc == 0) return;

    const long Mrows = (long)Bc * TOKENS;
    const long Mpad  = ((Mrows + 127) / 128) * 128;
    const int  NP    = Bc * 4;
    const int  gy    = (int)(Mpad / 128);
    const long patRows = ((long)Bc * 576 + 127) / 128 * 128;

    char* base = (char*)d_ws;
    float* tokf = (float*)(base + o_tokf);
    bf16*  xb   = (bf16*)(base + o_xb);
    char*  R1   = base + o_R1;
    char*  R2   = base + o_R2;
    bf16*  ob   = (bf16*)(base + o_ob);
    bf16*  wpT  = (bf16*)(base + o_wp);
    bf16*  wqkvT = (bf16*)(base + o_wr);
    bf16*  w0T   = wqkvT + 1536 * 512;
    bf16*  w1T   = w0T   + 512 * 512;
    bf16*  w2T   = w1T   + 2048 * 512;

    u16*  qkvb = (u16*)R1;
    bf16* pat  = (bf16*)R1;
    u16*  h1b  = (u16*)R1;
    u16*  vhT  = (u16*)R2;
    float* t1  = (float*)R2;

    wtrans<false><<<dim3(512 / 32, 768 / 32), 256, 0, stream>>>(Wpatch, wpT, 768, 512);

    const int nchunks = 32 / Bc;
    for (int ch = 0; ch < nchunks; ++ch) {
        const float* img_c = img + (long)ch * Bc * 3 * 384 * 384;

        // embed
        hipMemsetAsync(xb, 0, (size_t)Mpad * 512 * 2, stream);   // pad rows -> exact 0
        clsfill<<<Bc * 2, 256, 0, stream>>>(clstk, pos, tokf, xb);
        patch_gather<<<Bc * 16 * 24, 64, 0, stream>>>(img_c, pat);
        gemm_bt<1, false><<<dim3(4, (int)(patRows / 128)), 256, 0, stream>>>(
            (const u16*)pat, 768, (const u16*)wpT, 768,
            tokf, xb, 512, bpatch, pos, 768, Bc * 576);

        for (int l = 0; l < 6; ++l) {
            // rotate this layer's weights to bf16 N x K (Wqkv column-permuted)
            wtrans<true ><<<dim3(1536 / 32, 512 / 32), 256, 0, stream>>>(
                Wqkv + (long)l * 512 * 1536, wqkvT, 512, 1536);
            wtrans<false><<<dim3(512 / 32, 512 / 32), 256, 0, stream>>>(
                W0 + (long)l * 512 * 512, w0T, 512, 512);
            wtrans<false><<<dim3(2048 / 32, 512 / 32), 256, 0, stream>>>(
                W1 + (long)l * 512 * 2048, w1T, 512, 2048);
            wtrans<false><<<dim3(512 / 32, 2048 / 32), 256, 0, stream>>>(
                W2 + (long)l * 2048 * 512, w2T, 2048, 512);

            // qkv = x @ Wqkv  (permuted cols: kk*512 + h*128 + d)
            gemm_bt<0, false><<<dim3(12, gy), 256, 0, stream>>>(
                (const u16*)xb, 512, (const u16*)wqkvT, 512,
                nullptr, (bf16*)qkvb, 1536, nullptr, nullptr, 512, (int)Mpad);

            repack_v<<<NP * 10, 256, 0, stream>>>(qkvb, vhT);
            attn_flash<<<dim3(5, NP), 256, 0, stream>>>(qkvb, vhT, ob);

            // proj: t1 = o @ W0   (t1 overwrites vhT — attention done)
            gemm_bt<0, false><<<dim3(4, gy), 256, 0, stream>>>(
                (const u16*)ob, 512, (const u16*)w0T, 512,
                t1, nullptr, 512, nullptr, nullptr, 512, (int)Mrows);
            resln<<<(int)((Mrows + 3) / 4), 256, 0, stream>>>(
                t1, tokf, g1 + l * 512, b1 + l * 512, tokf, xb, (int)Mrows);
            // h1 = gelu(y @ W1 + bb1)   (h1b overwrites qkv — dead)
            gemm_bt<0, true><<<dim3(16, gy), 256, 0, stream>>>(
                (const u16*)xb, 512, (const u16*)w1T, 512,
                nullptr, (bf16*)h1b, 2048, bb1 + l * 2048, nullptr, 512, (int)Mpad);
            // t1 = h1 @ W2 + bb2
            gemm_bt<0, false><<<dim3(4, gy), 256, 0, stream>>>(
                (const u16*)h1b, 2048, (const u16*)w2T, 2048,
                t1, nullptr, 512, bb2 + l * 512, nullptr, 2048, (int)Mrows);
            resln<<<(int)((Mrows + 3) / 4), 256, 0, stream>>>(
                t1, tokf, g2 + l * 512, b2 + l * 512, tokf, xb, (int)Mrows);
        }

        head_k<<<Bc, 64, 0, stream>>>(tokf, Whead, bhead, (float*)d_out + (long)ch * Bc * 10);
    }
}

// Round 4
// 3292.965 us; speedup vs baseline: 1.7115x; 1.0001x over previous
//
#include <hip/hip_runtime.h>
#include <hip/hip_bf16.h>

// ViT forward, MI355X. 256x256 double-buffered 2-phase bf16 MFMA GEMM with
// T2 XOR-swizzled LDS (pre-swizzled global source + swizzled ds_read),
// fused flash attention, f32 residual/LN. Adaptive workspace via batch chunking.

typedef unsigned short u16;
typedef __hip_bfloat16 bf16;
typedef __bf16 bf16x8 __attribute__((ext_vector_type(8)));
typedef float f32x4 __attribute__((ext_vector_type(4)));

typedef const __attribute__((address_space(1))) void* gas_ptr;
typedef __attribute__((address_space(3))) void* las_ptr;

#define TOKENS 577
#define TPAD   640
#define DMODEL 512
#define SM_SCALE 0.08838834764831845f   /* 128^-0.5 */

static __device__ __forceinline__ u16 f2b(float v) {
    bf16 t = __float2bfloat16(v);
    return *(u16*)&t;
}

// ---------------------------------------------------------------------------
// 256x256 (or 256x128) tile GEMM: C[M,N] = A[M,K] @ Bt[N,K]^T (+bias)(+gelu)
// 512 threads = 8 waves (2M x 4N). BK=64. Double-buffered LDS, one barrier
// per K-step (stage k+1 issued before compute on k -> latency hidden).
// LDS tiles XOR-swizzled: LDS[row][s] holds global k-octet (s ^ (row&7)).
// OUTMODE 0: C row = m.  OUTMODE 1: patch-embed (row remap b*577+1+t, +pos).
// ---------------------------------------------------------------------------
template<int OUTMODE, bool GELU, int BN>
__global__ __launch_bounds__(512, 2)
void gemm2(const u16* __restrict__ A, int lda,
           const u16* __restrict__ Bt, int ldb,
           float* __restrict__ Cf, bf16* __restrict__ Cb, int ldc,
           const float* __restrict__ bias, const float* __restrict__ pos,
           int K, int rows_valid)
{
    constexpr int FN = BN / 64;          // B fragments per wave (4 or 2)
    constexpr int BLOADS = BN / 64;      // B gload_lds per thread (4 or 2)
    __shared__ u16 As[2][256 * 64];
    __shared__ u16 Bs[2][BN * 64];
    const int tid  = threadIdx.x;
    const int wid  = tid >> 6;
    const int lane = tid & 63;
    const int wm = wid >> 2, wn = wid & 3;
    const int lr = lane & 15, lg = lane >> 4;
    const u16* Ab = A + (long)blockIdx.y * 256 * lda;
    const u16* Bb = Bt + (long)blockIdx.x * BN * ldb;

    // staging geometry: one gload_lds = 512 thr x 16B = 64 rows of 128B
    const int srow = tid >> 3;                       // 0..63
    const int skswz = ((tid & 7) ^ (srow & 7)) * 8;  // pre-swizzled k element

    f32x4 acc[8][FN] = {};

#define STAGE(buf, kt)                                                          \
    {                                                                           \
        const int kb = (kt) * 64;                                               \
        _Pragma("unroll")                                                       \
        for (int i = 0; i < 4; ++i)                                             \
            __builtin_amdgcn_global_load_lds(                                   \
                (gas_ptr)(Ab + (long)(i * 64 + srow) * lda + kb + skswz),       \
                (las_ptr)&As[buf][(i * 64 + wid * 8) * 64], 16, 0, 0);          \
        _Pragma("unroll")                                                       \
        for (int i = 0; i < BLOADS; ++i)                                        \
            __builtin_amdgcn_global_load_lds(                                   \
                (gas_ptr)(Bb + (long)(i * 64 + srow) * ldb + kb + skswz),       \
                (las_ptr)&Bs[buf][(i * 64 + wid * 8) * 64], 16, 0, 0);          \
    }

    STAGE(0, 0);
    __syncthreads();   // vmcnt(0) drain + barrier (compiler-emitted)

    const int nt = K / 64;
    for (int kt = 0; kt < nt; ++kt) {
        const int cur = kt & 1;
        if (kt + 1 < nt) STAGE(cur ^ 1, kt + 1);     // issue BEFORE compute
#pragma unroll
        for (int kk = 0; kk < 2; ++kk) {
            const int ksl8 = ((kk * 4 + lg) ^ (lr & 7)) * 8;  // swizzled slot
            bf16x8 af[8], bv[FN];
#pragma unroll
            for (int m = 0; m < 8; ++m)
                af[m] = *(const bf16x8*)&As[cur][(wm * 128 + m * 16 + lr) * 64 + ksl8];
#pragma unroll
            for (int n = 0; n < FN; ++n)
                bv[n] = *(const bf16x8*)&Bs[cur][(wn * (FN * 16) + n * 16 + lr) * 64 + ksl8];
#pragma unroll
            for (int m = 0; m < 8; ++m)
#pragma unroll
                for (int n = 0; n < FN; ++n)
                    acc[m][n] = __builtin_amdgcn_mfma_f32_16x16x32_bf16(af[m], bv[n], acc[m][n], 0, 0, 0);
        }
        __syncthreads();   // drains next-tile loads (in flight during compute)
    }
#undef STAGE

    const int cbase = blockIdx.x * BN + wn * (FN * 16);
    const int rbase = blockIdx.y * 256 + wm * 128;
#pragma unroll
    for (int n = 0; n < FN; ++n) {
        const int c = cbase + n * 16 + lr;
        const float bval = bias ? bias[c] : 0.0f;
#pragma unroll
        for (int m = 0; m < 8; ++m) {
#pragma unroll
            for (int j = 0; j < 4; ++j) {
                const int r = rbase + m * 16 + lg * 4 + j;
                if (r >= rows_valid) continue;
                float v = acc[m][n][j] + bval;
                if constexpr (GELU) v = 0.5f * v * (1.0f + erff(v * 0.70710678118654752f));
                long idx;
                if constexpr (OUTMODE == 1) {
                    const int pb = r / 576, pt = r - pb * 576;
                    v += pos[(long)(1 + pt) * DMODEL + c];
                    idx = (long)(pb * TOKENS + 1 + pt) * ldc + c;
                } else {
                    idx = (long)r * ldc + c;
                }
                if (Cf) Cf[idx] = v;
                if (Cb) Cb[idx] = __float2bfloat16(v);
            }
        }
    }
}

// ---------------------------------------------------------------------------
// Fused flash attention. Grid: (5 q-tiles, NP pairs). 256 threads = 4 waves.
// qkv layout (permuted): [row][ kk*512 + h*128 + d ], row = b*577 + t (+pad).
// ---------------------------------------------------------------------------
__global__ __launch_bounds__(256, 2)
void attn_flash(const u16* __restrict__ qkv, const u16* __restrict__ vhT,
                bf16* __restrict__ ob)
{
    __shared__ u16 ldsA[128 * 128];   // K tile, then P tile
    __shared__ u16 ldsB[128 * 128];   // V^T tile [d][kv]
    const int tid = threadIdx.x;
    const int w = tid >> 6, lane = tid & 63;
    const int lr = lane & 15, lg = lane >> 4;
    const int pair = blockIdx.y;
    const int b = pair >> 2, h = pair & 3;
    const int q0 = blockIdx.x * 128;
    const long rowbase = (long)b * TOKENS;

    bf16x8 qf[2][4];
#pragma unroll
    for (int m = 0; m < 2; ++m)
#pragma unroll
        for (int kf = 0; kf < 4; ++kf) {
            const long r = rowbase + q0 + w * 32 + m * 16 + lr;
            qf[m][kf] = *(const bf16x8*)&qkv[r * 1536 + h * 128 + kf * 32 + lg * 8];
        }

    float mrun[2][4], lrun[2][4];
#pragma unroll
    for (int m = 0; m < 2; ++m)
#pragma unroll
        for (int j = 0; j < 4; ++j) { mrun[m][j] = -1e30f; lrun[m][j] = 0.f; }
    f32x4 oacc[2][8] = {};

    for (int kv0 = 0; kv0 < TPAD; kv0 += 128) {
        {
            const u16* kg = qkv + (rowbase + kv0) * 1536 + 512 + h * 128;
            const u16* vg = vhT + ((long)pair * 128) * TPAD + kv0;
#pragma unroll
            for (int p = 0; p < 8; ++p) {
                const int i = p * 16 + w * 4 + lg;
                __builtin_amdgcn_global_load_lds((gas_ptr)(kg + (long)i * 1536 + lr * 8),
                                                 (las_ptr)&ldsA[(p * 16 + w * 4) * 128], 16, 0, 0);
                __builtin_amdgcn_global_load_lds((gas_ptr)(vg + (long)i * TPAD + lr * 8),
                                                 (las_ptr)&ldsB[(p * 16 + w * 4) * 128], 16, 0, 0);
            }
        }
        __syncthreads();

        f32x4 s[2][8] = {};
#pragma unroll
        for (int kf = 0; kf < 4; ++kf) {
            bf16x8 bv[8];
#pragma unroll
            for (int n = 0; n < 8; ++n)
                bv[n] = *(const bf16x8*)&ldsA[(n * 16 + lr) * 128 + kf * 32 + lg * 8];
#pragma unroll
            for (int m = 0; m < 2; ++m)
#pragma unroll
                for (int n = 0; n < 8; ++n)
                    s[m][n] = __builtin_amdgcn_mfma_f32_16x16x32_bf16(qf[m][kf], bv[n], s[m][n], 0, 0, 0);
        }

        float sc[2][4];
#pragma unroll
        for (int m = 0; m < 2; ++m)
#pragma unroll
            for (int jj = 0; jj < 4; ++jj) {
                float mx = mrun[m][jj];
#pragma unroll
                for (int n = 0; n < 8; ++n) {
                    const int col = kv0 + n * 16 + lr;
                    float v = s[m][n][jj] * SM_SCALE;
                    v = (col < TOKENS) ? v : -1e30f;
                    s[m][n][jj] = v;
                    mx = fmaxf(mx, v);
                }
#pragma unroll
                for (int o = 1; o < 16; o <<= 1) mx = fmaxf(mx, __shfl_xor(mx, o));
                const float f = __expf(mrun[m][jj] - mx);
                sc[m][jj] = f;
                float sum = 0.f;
#pragma unroll
                for (int n = 0; n < 8; ++n) {
                    const float p = __expf(s[m][n][jj] - mx);
                    s[m][n][jj] = p;
                    sum += p;
                }
#pragma unroll
                for (int o = 1; o < 16; o <<= 1) sum += __shfl_xor(sum, o);
                lrun[m][jj] = lrun[m][jj] * f + sum;
                mrun[m][jj] = mx;
            }
#pragma unroll
        for (int m = 0; m < 2; ++m)
#pragma unroll
            for (int n = 0; n < 8; ++n)
#pragma unroll
                for (int jj = 0; jj < 4; ++jj) oacc[m][n][jj] *= sc[m][jj];

        __syncthreads();
#pragma unroll
        for (int m = 0; m < 2; ++m)
#pragma unroll
            for (int n = 0; n < 8; ++n)
#pragma unroll
                for (int jj = 0; jj < 4; ++jj)
                    ldsA[(w * 32 + m * 16 + lg * 4 + jj) * 128 + n * 16 + lr] = f2b(s[m][n][jj]);
        __syncthreads();

#pragma unroll
        for (int kf = 0; kf < 4; ++kf) {
            bf16x8 pa[2];
#pragma unroll
            for (int m = 0; m < 2; ++m)
                pa[m] = *(const bf16x8*)&ldsA[(w * 32 + m * 16 + lr) * 128 + kf * 32 + lg * 8];
#pragma unroll
            for (int n = 0; n < 8; ++n) {
                const bf16x8 vb = *(const bf16x8*)&ldsB[(n * 16 + lr) * 128 + kf * 32 + lg * 8];
#pragma unroll
                for (int m = 0; m < 2; ++m)
                    oacc[m][n] = __builtin_amdgcn_mfma_f32_16x16x32_bf16(pa[m], vb, oacc[m][n], 0, 0, 0);
            }
        }
        __syncthreads();
    }

#pragma unroll
    for (int m = 0; m < 2; ++m)
#pragma unroll
        for (int jj = 0; jj < 4; ++jj) {
            const float inv = 1.f / lrun[m][jj];
            const int q = q0 + w * 32 + m * 16 + lg * 4 + jj;
            if (q >= TOKENS) continue;
#pragma unroll
            for (int n = 0; n < 8; ++n)
                ob[(rowbase + q) * DMODEL + h * 128 + n * 16 + lr] =
                    __float2bfloat16(oacc[m][n][jj] * inv);
        }
}

// ---------------------------------------------------------------------------
// Weight transpose + f32->bf16:  WT[n][k] = bf16(W[k][n]).
// QKVPERM: output row n' = kk*512 + h*128 + d  for original col n = d*12+kk*4+h
// ---------------------------------------------------------------------------
template<bool QKVPERM>
__global__ __launch_bounds__(256)
void wtrans(const float* __restrict__ W, bf16* __restrict__ WT, int K, int N)
{
    __shared__ float tile[32][33];
    const int n0 = blockIdx.x * 32, k0 = blockIdx.y * 32;
    const int tx = threadIdx.x & 31, ty = threadIdx.x >> 5;
#pragma unroll
    for (int i = 0; i < 4; ++i)
        tile[ty + i * 8][tx] = W[(long)(k0 + ty + i * 8) * N + n0 + tx];
    __syncthreads();
#pragma unroll
    for (int i = 0; i < 4; ++i) {
        int n = n0 + ty + i * 8;
        if constexpr (QKVPERM) {
            const int d = n / 12, r = n % 12;
            n = (r >> 2) * 512 + (r & 3) * 128 + d;
        }
        WT[(long)n * K + k0 + tx] = __float2bfloat16(tile[tx][ty + i * 8]);
    }
}

// ---------------------------------------------------------------------------
// Patch gather: img (Bc,3,384,384) -> pat[b*576 + x*24+y][p1*48 + p2*3 + c] bf16
// ---------------------------------------------------------------------------
__global__ __launch_bounds__(64)
void patch_gather(const float* __restrict__ img, bf16* __restrict__ pat)
{
    const int bid = blockIdx.x;
    const int x  = bid % 24;
    const int p1 = (bid / 24) % 16;
    const int b  = bid / (24 * 16);
    __shared__ bf16 lds[24][48];
    const int lane = threadIdx.x;
    const int h = p1 * 24 + x;
    for (int c = 0; c < 3; ++c) {
        const float* row = img + ((long)(b * 3 + c) * 384 + h) * 384;
#pragma unroll
        for (int i = 0; i < 6; ++i) {
            const int wpix = lane + i * 64;
            const float v = row[wpix];
            const int y = wpix % 24, p2 = wpix / 24;
            lds[y][p2 * 3 + c] = __float2bfloat16(v);
        }
    }
    __syncthreads();
    for (int idx = lane; idx < 24 * 48; idx += 64) {
        const int y = idx / 48, j = idx % 48;
        pat[(long)(b * 576 + x * 24 + y) * 768 + p1 * 48 + j] = lds[y][j];
    }
}

// cls token row
__global__ __launch_bounds__(256)
void clsfill(const float* __restrict__ cls, const float* __restrict__ pos,
             float* __restrict__ tokf, bf16* __restrict__ xb)
{
    const int i = blockIdx.x * 256 + threadIdx.x;
    const int b = i >> 9, d = i & 511;
    const float v = cls[d] + pos[d];
    tokf[(long)b * TOKENS * DMODEL + d] = v;
    xb[(long)b * TOKENS * DMODEL + d] = __float2bfloat16(v);
}

// ---------------------------------------------------------------------------
// v (qkv permuted col 1024 + h*128 + d) -> vhT[(pair)*128 + d][t], t>=577 -> 0
// ---------------------------------------------------------------------------
__global__ __launch_bounds__(256)
void repack_v(const u16* __restrict__ qkv, u16* __restrict__ vhT)
{
    __shared__ u16 lds[64][136];
    const int bid = blockIdx.x;               // (pair, tt)
    const int tt = bid % 10, pair = bid / 10;
    const int b = pair >> 2, h = pair & 3;
    const int tid = threadIdx.x;
    const int tl = tid >> 2, seg = tid & 3;
    const long row = (long)b * TOKENS + tt * 64 + tl;
    const u16* src = qkv + row * 1536 + 1024 + h * 128 + seg * 32;
#pragma unroll
    for (int u = 0; u < 4; ++u)
        *(uint4*)&lds[tl][seg * 32 + u * 8] = *(const uint4*)&src[u * 8];
    __syncthreads();
    const int d = tid >> 1, th = (tid & 1) * 32;
    u16* dst = vhT + ((long)pair * 128 + d) * TPAD + tt * 64 + th;
#pragma unroll
    for (int blk = 0; blk < 4; ++blk) {
        uint4 pk; u16* pp = (u16*)&pk;
#pragma unroll
        for (int j = 0; j < 8; ++j) {
            const int t = tt * 64 + th + blk * 8 + j;
            pp[j] = (t < TOKENS) ? lds[th + blk * 8 + j][d] : (u16)0;
        }
        *(uint4*)&dst[blk * 8] = pk;
    }
}

// ---------------------------------------------------------------------------
// y = LN(xin + res)*g + b  -> outf (may alias res) and outb (bf16)
// ---------------------------------------------------------------------------
__global__ __launch_bounds__(256)
void resln(const float* __restrict__ xin, const float* __restrict__ res,
           const float* __restrict__ g, const float* __restrict__ b,
           float* __restrict__ outf, bf16* __restrict__ outb, int nrows)
{
    const int row = blockIdx.x * 4 + (threadIdx.x >> 6);
    if (row >= nrows) return;
    const int lane = threadIdx.x & 63;
    const float* p1 = xin + (long)row * DMODEL;
    const float* p2 = res + (long)row * DMODEL;
    float v[8];
    float s = 0.f;
#pragma unroll
    for (int i = 0; i < 8; ++i) { v[i] = p1[lane + i * 64] + p2[lane + i * 64]; s += v[i]; }
#pragma unroll
    for (int o = 32; o; o >>= 1) s += __shfl_xor(s, o);
    const float mean = s * (1.f / 512.f);
    float q = 0.f;
#pragma unroll
    for (int i = 0; i < 8; ++i) { const float d = v[i] - mean; q += d * d; }
#pragma unroll
    for (int o = 32; o; o >>= 1) q += __shfl_xor(q, o);
    const float rs = rsqrtf(q * (1.f / 512.f) + 1e-5f);
#pragma unroll
    for (int i = 0; i < 8; ++i) {
        const int c = lane + i * 64;
        const float o = (v[i] - mean) * rs * g[c] + b[c];
        outf[(long)row * DMODEL + c] = o;
        outb[(long)row * DMODEL + c] = __float2bfloat16(o);
    }
}

// Head: out[b][c] = tok[b*577][:] . Whead[:,c] + bhead[c]
__global__ __launch_bounds__(64)
void head_k(const float* __restrict__ tokf, const float* __restrict__ Wh,
            const float* __restrict__ bh, float* __restrict__ out)
{
    const int b = blockIdx.x;
    const int lane = threadIdx.x;
    const float* x = tokf + (long)b * TOKENS * DMODEL;
    float acc[10] = {};
#pragma unroll
    for (int i = 0; i < 8; ++i) {
        const int d = lane + i * 64;
        const float xv = x[d];
        const float* wr = Wh + (long)d * 10;
#pragma unroll
        for (int c = 0; c < 10; ++c) acc[c] += xv * wr[c];
    }
#pragma unroll
    for (int c = 0; c < 10; ++c)
#pragma unroll
        for (int o = 32; o; o >>= 1) acc[c] += __shfl_xor(acc[c], o);
    if (lane == 0) {
#pragma unroll
        for (int c = 0; c < 10; ++c) out[b * 10 + c] = acc[c] + bh[c];
    }
}

// ---------------------------------------------------------------------------
extern "C" void kernel_launch(void* const* d_in, const int* in_sizes, int n_in,
                              void* d_out, int out_size, void* d_ws, size_t ws_size,
                              hipStream_t stream)
{
    (void)in_sizes; (void)n_in; (void)out_size;
    const float* img    = (const float*)d_in[0];
    const float* Wpatch = (const float*)d_in[1];
    const float* bpatch = (const float*)d_in[2];
    const float* clstk  = (const float*)d_in[3];
    const float* pos    = (const float*)d_in[4];
    const float* Wqkv   = (const float*)d_in[5];
    const float* W0     = (const float*)d_in[6];
    const float* g1     = (const float*)d_in[7];
    const float* b1     = (const float*)d_in[8];
    const float* g2     = (const float*)d_in[9];
    const float* b2     = (const float*)d_in[10];
    const float* W1     = (const float*)d_in[11];
    const float* bb1    = (const float*)d_in[12];
    const float* W2     = (const float*)d_in[13];
    const float* bb2    = (const float*)d_in[14];
    const float* Whead  = (const float*)d_in[15];
    const float* bhead  = (const float*)d_in[16];

    // ---- pick the largest batch chunk that fits ws (M padded to 256) ----
    static const int cand[6] = {32, 16, 8, 4, 2, 1};
    int Bc = 0;
    size_t o_tokf=0, o_xb=0, o_R1=0, o_R2=0, o_ob=0, o_wp=0, o_wr=0;
    for (int ci = 0; ci < 6; ++ci) {
        const int bc = cand[ci];
        const long Mrows = (long)bc * TOKENS;
        const long Mpad  = ((Mrows + 255) / 256) * 256;
        size_t off = 0;
        auto take = [&](size_t sz) { size_t o = off; off += (sz + 255) & ~(size_t)255; return o; };
        size_t t_tokf = take((size_t)Mpad * 512 * 4);
        size_t t_xb   = take((size_t)Mpad * 512 * 2);
        size_t t_R1   = take((size_t)Mpad * 2048 * 2);          // pat | qkv | h1b
        size_t t_R2   = take((size_t)Mpad * 512 * 4);           // vhT | t1
        size_t t_ob   = take((size_t)Mpad * 512 * 2);
        size_t t_wp   = take((size_t)512 * 768 * 2);
        size_t t_wr   = take((size_t)3145728 * 2);              // rotating layer weights
        if (off <= ws_size) {
            Bc = bc;
            o_tokf=t_tokf; o_xb=t_xb; o_R1=t_R1; o_R2=t_R2; o_ob=t_ob; o_wp=t_wp; o_wr=t_wr;
            break;
        }
    }
    if (Bc == 0) return;

    const long Mrows = (long)Bc * TOKENS;
    const long Mpad  = ((Mrows + 255) / 256) * 256;
    const int  NP    = Bc * 4;
    const int  gy    = (int)(Mpad / 256);
    const int  gyp   = (int)(((long)Bc * 576 + 255) / 256);

    char* base = (char*)d_ws;
    float* tokf = (float*)(base + o_tokf);
    bf16*  xb   = (bf16*)(base + o_xb);
    char*  R1   = base + o_R1;
    char*  R2   = base + o_R2;
    bf16*  ob   = (bf16*)(base + o_ob);
    bf16*  wpT  = (bf16*)(base + o_wp);
    bf16*  wqkvT = (bf16*)(base + o_wr);
    bf16*  w0T   = wqkvT + 1536 * 512;
    bf16*  w1T   = w0T   + 512 * 512;
    bf16*  w2T   = w1T   + 2048 * 512;

    u16*  qkvb = (u16*)R1;
    bf16* pat  = (bf16*)R1;
    u16*  h1b  = (u16*)R1;
    u16*  vhT  = (u16*)R2;
    float* t1  = (float*)R2;

    wtrans<false><<<dim3(512 / 32, 768 / 32), 256, 0, stream>>>(Wpatch, wpT, 768, 512);

    const int nchunks = 32 / Bc;
    for (int ch = 0; ch < nchunks; ++ch) {
        const float* img_c = img + (long)ch * Bc * 3 * 384 * 384;

        // embed
        hipMemsetAsync(xb, 0, (size_t)Mpad * 512 * 2, stream);   // pad rows -> exact 0
        clsfill<<<Bc * 2, 256, 0, stream>>>(clstk, pos, tokf, xb);
        patch_gather<<<Bc * 16 * 24, 64, 0, stream>>>(img_c, pat);
        gemm2<1, false, 128><<<dim3(4, gyp), 512, 0, stream>>>(
            (const u16*)pat, 768, (const u16*)wpT, 768,
            tokf, xb, 512, bpatch, pos, 768, Bc * 576);

        for (int l = 0; l < 6; ++l) {
            // rotate this layer's weights to bf16 N x K (Wqkv column-permuted)
            wtrans<true ><<<dim3(1536 / 32, 512 / 32), 256, 0, stream>>>(
                Wqkv + (long)l * 512 * 1536, wqkvT, 512, 1536);
            wtrans<false><<<dim3(512 / 32, 512 / 32), 256, 0, stream>>>(
                W0 + (long)l * 512 * 512, w0T, 512, 512);
            wtrans<false><<<dim3(2048 / 32, 512 / 32), 256, 0, stream>>>(
                W1 + (long)l * 512 * 2048, w1T, 512, 2048);
            wtrans<false><<<dim3(512 / 32, 2048 / 32), 256, 0, stream>>>(
                W2 + (long)l * 2048 * 512, w2T, 2048, 512);

            // qkv = x @ Wqkv  (permuted cols: kk*512 + h*128 + d)
            gemm2<0, false, 256><<<dim3(6, gy), 512, 0, stream>>>(
                (const u16*)xb, 512, (const u16*)wqkvT, 512,
                nullptr, (bf16*)qkvb, 1536, nullptr, nullptr, 512, (int)Mpad);

            repack_v<<<NP * 10, 256, 0, stream>>>(qkvb, vhT);
            attn_flash<<<dim3(5, NP), 256, 0, stream>>>(qkvb, vhT, ob);

            // proj: t1 = o @ W0   (t1 overwrites vhT — attention done)
            gemm2<0, false, 128><<<dim3(4, gy), 512, 0, stream>>>(
                (const u16*)ob, 512, (const u16*)w0T, 512,
                t1, nullptr, 512, nullptr, nullptr, 512, (int)Mrows);
            resln<<<(int)((Mrows + 3) / 4), 256, 0, stream>>>(
                t1, tokf, g1 + l * 512, b1 + l * 512, tokf, xb, (int)Mrows);
            // h1 = gelu(y @ W1 + bb1)   (h1b overwrites qkv — dead)
            gemm2<0, true, 256><<<dim3(8, gy), 512, 0, stream>>>(
                (const u16*)xb, 512, (const u16*)w1T, 512,
                nullptr, (bf16*)h1b, 2048, bb1 + l * 2048, nullptr, 512, (int)Mpad);
            // t1 = h1 @ W2 + bb2
            gemm2<0, false, 128><<<dim3(4, gy), 512, 0, stream>>>(
                (const u16*)h1b, 2048, (const u16*)w2T, 2048,
                t1, nullptr, 512, bb2 + l * 512, nullptr, 2048, (int)Mrows);
            resln<<<(int)((Mrows + 3) / 4), 256, 0, stream>>>(
                t1, tokf, g2 + l * 512, b2 + l * 512, tokf, xb, (int)Mrows);
        }

        head_k<<<Bc, 64, 0, stream>>>(tokf, Whead, bhead, (float*)d_out + (long)ch * Bc * 10);
    }
}